// Round 8
// baseline (149.780 us; speedup 1.0000x reference)
//
#include <hip/hip_runtime.h>
#include <hip/hip_bf16.h>

// CapsuleLayer on MI355X — R12: barrier-free + ≤128-total-reg occupancy bucket.
// m69: wave slots bucket at total regs {64,128,256}: ≤128 -> 4 waves/SIMD.
// All prior acc[4][4] variants (incl. R11) were 180-196 regs -> 2 waves/SIMD
// -> latency-exposed regardless of schedule. This round: wave = 4r x 16c x
// 32co (acc[4][2]=32 AGPR), 8 waves/block (rg2 x cg4), A parity-prefetch at
// half-kk from LDS, B parity-prefetch at full-kk from fragment-ordered Wr2b
// (L2-resident), ZERO mid-loop barriers, __launch_bounds__(512,4).
// b stays 0 (faithful torch bug) => one dense conv 64ci->128co, 5x5, pad 2;
// v = squash_z1(p/(8*cnt)); out [N, t1, z1, H, W].

#define CO 128

typedef __attribute__((ext_vector_type(8))) short bf16x8;
typedef __attribute__((ext_vector_type(4))) float f32x4;

// ---- fused prep:
//   blocks [0,800):    W fp32 [t0][co][z0][5][5] -> Wr2b bf16 fragment-order:
//                      oi = ((((kk*4+cg)*2+ks)*2+ni)<<9) + ((q*16+m16)<<3) + j
//                      (co = cg*32+ni*16+m16, ci = ks*32+q*8+j)
//   blocks [800,1824): u [n][ci][h][w] fp32 -> ut [n][h][w][ci] bf16
__global__ __launch_bounds__(256) void k_prep(const float* __restrict__ u,
                                              const float* __restrict__ Wsrc,
                                              ushort* __restrict__ ut,
                                              ushort* __restrict__ Wr2b) {
    __shared__ float lt[64][65];
    int b = blockIdx.x;
    int t = threadIdx.x;
    if (b < 800) {
        int idx = b * 256 + t;                  // 25*128*64 exact
        int ci = idx & 63;
        int r  = idx >> 6;
        int co = r & 127;
        int kk = r >> 7;
        int t0 = ci >> 4, z0 = ci & 15;
        __hip_bfloat16 bb = __float2bfloat16(Wsrc[((t0 * CO + co) * 16 + z0) * 25 + kk]);
        int cg = co >> 5, ni = (co >> 4) & 1, m16 = co & 15;
        int ks = ci >> 5, q = (ci >> 3) & 3, j = ci & 7;
        int oi = ((((kk * 4 + cg) * 2 + ks) * 2 + ni) << 9) + ((q * 16 + m16) << 3) + j;
        Wr2b[oi] = *(ushort*)&bb;
        return;
    }
    b -= 800;                                   // (n*128 + h)*2 + wchunk
    int wc = b & 1; int nh = b >> 1; int h = nh & 127; int n = nh >> 7;
    int w0 = wc * 64;
    int ciL = t >> 4;
    int wl  = (t & 15) * 4;
    const float* up = u + (size_t)n * (64 * 128 * 128) + h * 128 + w0;
#pragma unroll
    for (int p = 0; p < 4; ++p) {
        int ci = p * 16 + ciL;
        float4 v = *(const float4*)(up + (size_t)ci * 16384 + wl);
        lt[wl + 0][ci] = v.x;
        lt[wl + 1][ci] = v.y;
        lt[wl + 2][ci] = v.z;
        lt[wl + 3][ci] = v.w;
    }
    __syncthreads();
    ushort* op = ut + (((size_t)(n * 128 + h)) * 128 + w0) * 64;
#pragma unroll
    for (int p = 0; p < 2; ++p) {
        int item = p * 256 + t;
        int c8 = item & 7, w2 = item >> 3;
        bf16x8 vv;
#pragma unroll
        for (int j = 0; j < 8; ++j) {
            __hip_bfloat16 bb = __float2bfloat16(lt[w2][c8 * 8 + j]);
            vv[j] = *(ushort*)&bb;
        }
        *(bf16x8*)(op + (size_t)w2 * 64 + c8 * 8) = vv;
    }
}

// ---- main: grid 512 = 4(n) x 16(by: 8 rows) x 8(bx: 16 cols), 512 thr =
// 8 waves = rg2(4 h-rows each) x cg4(32 co each). acc[4][2] = 32 AGPR.
// As stride-68 (HW-verified conflict-free), all ds_read offsets immediates.
// ZERO mid-loop barriers; A parity dbuf per half-kk; B parity dbuf per kk.
__global__ __launch_bounds__(512, 4) void k_caps(const ushort* __restrict__ ut,
                                                 const ushort* __restrict__ Wr2b,
                                                 float* __restrict__ out) {
    __shared__ ushort As[240 * 68];      // 32640 B

    int tid = threadIdx.x;
    int bid = blockIdx.x;
    int bx = bid & 7, by = (bid >> 3) & 15, n = bid >> 7;
    int h0 = by * 8, w0 = bx * 16;

    int lane = tid & 63, wid = tid >> 6;
    int rg = wid >> 2;                   // h group (0..1): rows [wm4, wm4+4)
    int cg = wid & 3;                    // co group: 32 co
    int wm4  = rg * 4;
    int wn32 = cg * 32;
    int q = lane >> 4, m16 = lane & 15;

    // B fragment base for this wave: frag(kk,ks,ni) = wp + kk*8192 + (ks*2+ni)*512
    const ushort* wp = Wr2b + ((size_t)cg * 2048) + lane * 8;

    bf16x8 bbuf[2][4];                   // [kk parity][ks*2+ni]
#define LOADB(par, kk2)                                                   \
    {                                                                     \
        _Pragma("unroll") for (int i_ = 0; i_ < 4; ++i_)                  \
            bbuf[par][i_] = *(const bf16x8*)(                             \
                wp + (size_t)(kk2) * 8192 + i_ * 512);                    \
    }

    LOADB(0, 0);                         // flies under the A staging

    // ---- A staging from ut: 1920 x 16B, 1KB-contiguous per wave pass.
    for (int i = tid; i < 1920; i += 512) {
        int p = i >> 3, c = i & 7;
        int rr = p / 20, cc = p - rr * 20;
        int hh = h0 + rr - 2, ww = w0 + cc - 2;
        bf16x8 v = {};
        if (((unsigned)hh < 128u) & ((unsigned)ww < 128u))
            v = *(const bf16x8*)(ut + (((size_t)(n * 128 + hh)) * 128 + ww) * 64 + c * 8);
        *(bf16x8*)&As[p * 68 + c * 8] = v;
    }
    __syncthreads();                     // the ONLY barrier

    // lane A base; per-(kk,mi,ks) deltas are compile-time immediates.
    const ushort* ap = As + (wm4 * 20 + m16) * 68 + q * 8;

    bf16x8 abuf[2][4];                   // [half-kk parity][mi]
#define LOADA(par, kk2, ks2)                                                \
    {                                                                       \
        const int kh_ = (kk2) / 5, kw_ = (kk2) % 5;                         \
        _Pragma("unroll") for (int mi_ = 0; mi_ < 4; ++mi_)                 \
            abuf[par][mi_] = *(const bf16x8*)(                              \
                ap + ((mi_ + kh_) * 20 + kw_) * 68 + (ks2) * 32);           \
    }

    LOADA(0, 0, 0);

    f32x4 acc[4][2] = {};

#pragma unroll
    for (int kk = 0; kk < 25; ++kk) {
#pragma unroll
        for (int ks = 0; ks < 2; ++ks) {
            const int h = kk * 2 + ks;
            // prefetch next half-kk's A frags BEFORE this half's MFMAs
            if (h + 1 < 50) { LOADA((h + 1) & 1, (h + 1) >> 1, (h + 1) & 1); }
            // prefetch next kk's B frags during ks=0 MFMAs (1 kk ahead)
            if (ks == 0 && kk < 24) { LOADB((kk + 1) & 1, kk + 1); }
#pragma unroll
            for (int mi = 0; mi < 4; ++mi)
#pragma unroll
                for (int ni = 0; ni < 2; ++ni)
                    acc[mi][ni] = __builtin_amdgcn_mfma_f32_16x16x32_bf16(
                        abuf[h & 1][mi], bbuf[kk & 1][ks * 2 + ni],
                        acc[mi][ni], 0, 0, 0);
        }
    }
#undef LOADA
#undef LOADB

    // epilogue (R3-proven): scale 1/(8*cnt), squash over z1 (m16 lanes), store
    // D layout: row(m = image col) = q*4+reg, col(n = co) = m16
#pragma unroll
    for (int mi = 0; mi < 4; ++mi) {
        int h = h0 + wm4 + mi;
        int hlo = h - 2; if (hlo < 0) hlo = 0;
        int hhi = h + 2; if (hhi > 127) hhi = 127;
        float cnth = (float)(hhi - hlo + 1);
#pragma unroll
        for (int ni = 0; ni < 2; ++ni) {
            f32x4 cv = acc[mi][ni];
            float ov[4];
#pragma unroll
            for (int reg = 0; reg < 4; ++reg) {
                int w = w0 + q * 4 + reg;
                int wlo = w - 2; if (wlo < 0) wlo = 0;
                int whi = w + 2; if (whi > 127) whi = 127;
                float s = 1.f / (8.f * cnth * (float)(whi - wlo + 1));
                float pv = cv[reg] * s;
                float n2 = pv * pv;
                n2 += __shfl_xor(n2, 1);
                n2 += __shfl_xor(n2, 2);
                n2 += __shfl_xor(n2, 4);
                n2 += __shfl_xor(n2, 8);
                float fac = n2 / ((1.f + n2) * sqrtf(n2 + 1e-9f));
                ov[reg] = pv * fac;
            }
            int co = wn32 + ni * 16 + m16;
            *(float4*)(out + (((size_t)(n * CO + co)) << 14) + h * 128 + w0 + q * 4) =
                make_float4(ov[0], ov[1], ov[2], ov[3]);
        }
    }
}

extern "C" void kernel_launch(void* const* d_in, const int* in_sizes, int n_in,
                              void* d_out, int out_size, void* d_ws, size_t ws_size,
                              hipStream_t stream) {
    const float* u    = (const float*)d_in[0];
    const float* Wsrc = (const float*)d_in[1];
    float* out = (float*)d_out;
    ushort* Wr2b = (ushort*)d_ws;                      // 409600 B
    ushort* ut   = (ushort*)((char*)d_ws + 409600);    // 8388608 B

    k_prep<<<1824, 256, 0, stream>>>(u, Wsrc, ut, Wr2b);
    k_caps<<<512, 512, 0, stream>>>(ut, Wr2b, out);
}